// Round 6
// baseline (438.628 us; speedup 1.0000x reference)
//
#include <hip/hip_runtime.h>

#define EPS 1e-5f

// ---------------------------------------------------------------------------
// K1: in-degree histogram (edges only; self-loop folded in as +1 later)
__global__ void count_kernel(const int* __restrict__ col, int* __restrict__ counts, int E) {
    int e = blockIdx.x * blockDim.x + threadIdx.x;
    if (e < E) atomicAdd(&counts[col[e]], 1);
}

// ---------------------------------------------------------------------------
// K2a: per-block (256 counts each) partial sums
__global__ void scan_reduce(const int* __restrict__ counts, int* __restrict__ blockSums, int N) {
    __shared__ int red[256];
    int i = blockIdx.x * 256 + threadIdx.x;
    red[threadIdx.x] = (i < N) ? counts[i] : 0;
    __syncthreads();
    for (int d = 128; d > 0; d >>= 1) {
        if (threadIdx.x < d) red[threadIdx.x] += red[threadIdx.x + d];
        __syncthreads();
    }
    if (threadIdx.x == 0) blockSums[blockIdx.x] = red[0];
}

// K2b: single-block exclusive scan over the (<=1024) block sums; writes offsets[N]=total
__global__ void scan_blocksums(int* __restrict__ blockSums, int* __restrict__ blockOffs,
                               int nb, int* __restrict__ offsets, int N) {
    __shared__ int s[1024];
    int tid = threadIdx.x;
    s[tid] = (tid < nb) ? blockSums[tid] : 0;
    __syncthreads();
    for (int d = 1; d < 1024; d <<= 1) {
        int v = (tid >= d) ? s[tid - d] : 0;
        __syncthreads();
        s[tid] += v;
        __syncthreads();
    }
    if (tid < nb) blockOffs[tid] = (tid == 0) ? 0 : s[tid - 1];
    if (tid == 1023) offsets[N] = s[1023];
}

// K2c: in-block exclusive scan of 256 counts + block offset -> offsets; dinv = rsqrt(deg+1)
__global__ void scan_apply(const int* __restrict__ counts, const int* __restrict__ blockOffs,
                           int* __restrict__ offsets, float* __restrict__ dinv, int N) {
    __shared__ int s[256];
    int tid = threadIdx.x;
    int i = blockIdx.x * 256 + tid;
    int c = (i < N) ? counts[i] : 0;
    s[tid] = c;
    __syncthreads();
    for (int d = 1; d < 256; d <<= 1) {
        int v = (tid >= d) ? s[tid - d] : 0;
        __syncthreads();
        s[tid] += v;
        __syncthreads();
    }
    if (i < N) {
        offsets[i] = blockOffs[blockIdx.x] + s[tid] - c;  // exclusive
        dinv[i] = rsqrtf((float)(c + 1));                 // +1 self loop; deg >= 1
    }
}

// ---------------------------------------------------------------------------
// K3: scatter edge sources into CSR buckets
__global__ void scatter_kernel(const int* __restrict__ row, const int* __restrict__ col,
                               const int* __restrict__ offsets, int* __restrict__ cursor,
                               int* __restrict__ csr, int E) {
    int e = blockIdx.x * blockDim.x + threadIdx.x;
    if (e < E) {
        int c = col[e];
        int pos = offsets[c] + atomicAdd(&cursor[c], 1);
        csr[pos] = row[e];
    }
}

// ---------------------------------------------------------------------------
// K4: xs = (x @ W.T) * dinv[row]  — W-RESIDENT, LDS-BW-balanced.
// R5 post-mortem: 4 cols x 4 rows/thread = 0.5 B LDS per FLOP = 128 B/cyc
// demand > 85 B/cyc LDS pipe -> LDS-BW-bound, VALUBusy capped ~34% and extra
// waves didn't help. Fix: 8 rows x 4 cols/thread (rows come from GLOBAL
// broadcast, not LDS) -> LDS demand halves per FLOP. One 128-row chunk per
// block, grid = ceil(N/128), no grid-stride. Staging loop fixed to 4096
// float4s (R4/R5 iterated 4x too far: OOB W reads + dropped OOB LDS writes).
// XOR swizzle (k ^ ((j&31)<<2)) keeps float4 contiguity, 0 bank conflicts.
__global__ __launch_bounds__(512, 4) void gemm_kernel(
    const float* __restrict__ x, const float* __restrict__ W,
    const float* __restrict__ dinv, float* __restrict__ xs, int N) {
    __shared__ float sw[128 * 128];  // 64 KB, element (j,k) at j*128 + (k ^ ((j&31)<<2))
    int tid = threadIdx.x;
    int c  = tid & 31;   // column lane: cols c + 32q
    int rg = tid >> 5;   // row group in [0,16): rows rg + 16i, i in [0,8)

    // stage W once: 4096 float4s, 8 per thread
#pragma unroll
    for (int t = 0; t < 8; ++t) {
        int idx = tid + t * 512;                   // [0,4096)
        int j = idx >> 5, k4 = idx & 31;           // j in [0,128), k4 in [0,32)
        float4 v = ((const float4*)W)[idx];
        *((float4*)&sw[j * 128 + ((k4 * 4) ^ ((j & 31) << 2))]) = v;
    }
    __syncthreads();

    int cswz = c << 2;  // swizzle offset for this lane's columns (j&31 == c for all q)
    int r0 = blockIdx.x * 128;

    const float4* xr[8];
    bool valid[8];
#pragma unroll
    for (int i = 0; i < 8; ++i) {
        int grow = r0 + rg + 16 * i;
        valid[i] = (grow < N);
        xr[i] = (const float4*)&x[(size_t)(valid[i] ? grow : 0) * 128];
    }

    float acc[8][4];
#pragma unroll
    for (int i = 0; i < 8; ++i)
#pragma unroll
        for (int q = 0; q < 4; ++q) acc[i][q] = 0.f;

#pragma unroll 4
    for (int k4 = 0; k4 < 32; ++k4) {
        float4 wv[4], xv[8];
#pragma unroll
        for (int q = 0; q < 4; ++q)
            wv[q] = *((const float4*)&sw[(c + 32 * q) * 128 + ((k4 * 4) ^ cswz)]);
#pragma unroll
        for (int i = 0; i < 8; ++i) xv[i] = xr[i][k4];
#pragma unroll
        for (int i = 0; i < 8; ++i)
#pragma unroll
            for (int q = 0; q < 4; ++q)
                acc[i][q] += xv[i].x * wv[q].x + xv[i].y * wv[q].y +
                             xv[i].z * wv[q].z + xv[i].w * wv[q].w;
    }

#pragma unroll
    for (int i = 0; i < 8; ++i) {
        int grow = r0 + rg + 16 * i;
        if (valid[i]) {
            float dv = dinv[grow];
#pragma unroll
            for (int q = 0; q < 4; ++q)
                xs[(size_t)grow * 128 + c + 32 * q] = acc[i][q] * dv;
        }
    }
}

// ---------------------------------------------------------------------------
// K5: gather aggregation, one wave per node; pre[n] = dinv[n]*(xs[n] + sum xs[src])
__global__ void gather_kernel(const float* __restrict__ xs, const float* __restrict__ dinv,
                              const int* __restrict__ offsets, const int* __restrict__ csr,
                              float* __restrict__ pre, int N) {
    int lane = threadIdx.x & 63;
    int wid = (blockIdx.x * blockDim.x + threadIdx.x) >> 6;
    int nw  = (gridDim.x * blockDim.x) >> 6;
    const float2* xs2 = (const float2*)xs;
    float2* pre2 = (float2*)pre;
    for (int n = wid; n < N; n += nw) {
        int s = offsets[n], e = offsets[n + 1];
        float2 acc = xs2[n * 64 + lane];  // self loop term
        int p = s;
        for (; p + 8 <= e; p += 8) {      // 8-deep ILP on the random gathers
            int idx[8];
#pragma unroll
            for (int t = 0; t < 8; ++t) idx[t] = csr[p + t];
            float2 a[8];
#pragma unroll
            for (int t = 0; t < 8; ++t) a[t] = xs2[idx[t] * 64 + lane];
#pragma unroll
            for (int t = 0; t < 8; ++t) { acc.x += a[t].x; acc.y += a[t].y; }
        }
        for (; p < e; ++p) {
            float2 a = xs2[csr[p] * 64 + lane];
            acc.x += a.x; acc.y += a.y;
        }
        float dv = dinv[n];
        pre2[n * 64 + lane] = make_float2(acc.x * dv, acc.y * dv);
    }
}

// ---------------------------------------------------------------------------
// K6: column sums + total sum of squares (for PairNorm via moment identity)
__global__ void moments_kernel(const float* __restrict__ pre, float* __restrict__ colsum,
                               float* __restrict__ sumsq, int total) {
    __shared__ float red[256];
    int tid = blockIdx.x * blockDim.x + threadIdx.x;
    int stride = gridDim.x * blockDim.x;  // multiple of 128 -> column fixed per thread
    float cs = 0.f, ss = 0.f;
    for (int i = tid; i < total; i += stride) {
        float v = pre[i];
        cs += v; ss += v * v;
    }
    red[threadIdx.x] = cs;
    __syncthreads();
    if (threadIdx.x < 128)
        atomicAdd(&colsum[threadIdx.x], red[threadIdx.x] + red[threadIdx.x + 128]);
    __syncthreads();
    red[threadIdx.x] = ss;
    __syncthreads();
    for (int d = 128; d > 0; d >>= 1) {
        if (threadIdx.x < d) red[threadIdx.x] += red[threadIdx.x + d];
        __syncthreads();
    }
    if (threadIdx.x == 0) atomicAdd(sumsq, red[0]);
}

// ---------------------------------------------------------------------------
// K7: tiny param kernel: colmean and global scale s
__global__ void params_kernel(const float* __restrict__ colsum, const float* __restrict__ sumsq,
                              float* __restrict__ mparams, int N) {
    int j = threadIdx.x;  // 128 threads
    float m = colsum[j] / (float)N;
    mparams[j] = m;
    __shared__ float red[128];
    red[j] = m * m;
    __syncthreads();
    for (int d = 64; d > 0; d >>= 1) {
        if (j < d) red[j] += red[j + d];
        __syncthreads();
    }
    if (j == 0) {
        float tot = sumsq[0] - (float)N * red[0];  // sum (out - m)^2
        mparams[128] = rsqrtf(EPS + tot / (float)N);
    }
}

// ---------------------------------------------------------------------------
// K8: in-place PairNorm apply + relu + residual:  y=(v-m_j)*s; out = y>0 ? 2y : y
__global__ void final_kernel(float* __restrict__ out, const float* __restrict__ mparams,
                             int total) {
    __shared__ float sm[129];
    if (threadIdx.x < 129) sm[threadIdx.x] = mparams[threadIdx.x];
    __syncthreads();
    float s = sm[128];
    int tid = blockIdx.x * blockDim.x + threadIdx.x;
    int stride = gridDim.x * blockDim.x;
    for (int i = tid; i < total; i += stride) {
        float y = (out[i] - sm[i & 127]) * s;
        out[i] = y > 0.f ? 2.f * y : y;
    }
}

// ---------------------------------------------------------------------------
extern "C" void kernel_launch(void* const* d_in, const int* in_sizes, int n_in,
                              void* d_out, int out_size, void* d_ws, size_t ws_size,
                              hipStream_t stream) {
    const float* x = (const float*)d_in[0];
    const float* W = (const float*)d_in[1];
    const int* ei  = (const int*)d_in[2];
    int N = in_sizes[0] / 128;
    int E = in_sizes[2] / 2;
    const int* row = ei;        // edge_index[0] = source
    const int* col = ei + E;    // edge_index[1] = aggregation target
    float* out = (float*)d_out;

    int nb = (N + 255) / 256;   // scan blocks (196 for N=50000; must be <= 1024)

    // workspace layout (all 4-byte elements)
    float* xs        = (float*)d_ws;            // N*128
    float* dinv      = xs + (size_t)N * 128;    // N
    int*   counts    = (int*)(dinv + N);        // N    [zeroed]
    int*   cursor    = counts + N;              // N    [zeroed]
    float* colsum    = (float*)(cursor + N);    // 128  [zeroed]
    float* sumsq     = colsum + 128;            // 1    [zeroed]
    int*   offsets   = (int*)(sumsq + 1);       // N+1
    int*   csr       = offsets + (N + 1);       // E
    float* mparams   = (float*)(csr + E);       // 129
    int*   blockSums = (int*)(mparams + 129);   // nb
    int*   blockOffs = blockSums + nb;          // nb

    hipMemsetAsync(counts, 0, (size_t)(2 * N + 129) * 4, stream);

    count_kernel  <<<(E + 255) / 256, 256, 0, stream>>>(col, counts, E);
    scan_reduce   <<<nb, 256, 0, stream>>>(counts, blockSums, N);
    scan_blocksums<<<1, 1024, 0, stream>>>(blockSums, blockOffs, nb, offsets, N);
    scan_apply    <<<nb, 256, 0, stream>>>(counts, blockOffs, offsets, dinv, N);
    scatter_kernel<<<(E + 255) / 256, 256, 0, stream>>>(row, col, offsets, cursor, csr, E);
    gemm_kernel   <<<(N + 127) / 128, 512, 0, stream>>>(x, W, dinv, xs, N);
    gather_kernel <<<2048, 256, 0, stream>>>(xs, dinv, offsets, csr, out, N);
    moments_kernel<<<512, 256, 0, stream>>>(out, colsum, sumsq, N * 128);
    params_kernel <<<1, 128, 0, stream>>>(colsum, sumsq, mparams, N);
    final_kernel  <<<1024, 256, 0, stream>>>(out, mparams, N * 128);
}

// Round 7
// 275.063 us; speedup vs baseline: 1.5946x; 1.5946x over previous
//
#include <hip/hip_runtime.h>

#define EPS 1e-5f

// ---------------------------------------------------------------------------
// K1: in-degree histogram (edges only; self-loop folded in as +1 later)
__global__ void count_kernel(const int* __restrict__ col, int* __restrict__ counts, int E) {
    int e = blockIdx.x * blockDim.x + threadIdx.x;
    if (e < E) atomicAdd(&counts[col[e]], 1);
}

// ---------------------------------------------------------------------------
// K2a: per-block (256 counts each) partial sums
__global__ void scan_reduce(const int* __restrict__ counts, int* __restrict__ blockSums, int N) {
    __shared__ int red[256];
    int i = blockIdx.x * 256 + threadIdx.x;
    red[threadIdx.x] = (i < N) ? counts[i] : 0;
    __syncthreads();
    for (int d = 128; d > 0; d >>= 1) {
        if (threadIdx.x < d) red[threadIdx.x] += red[threadIdx.x + d];
        __syncthreads();
    }
    if (threadIdx.x == 0) blockSums[blockIdx.x] = red[0];
}

// K2b: single-block exclusive scan over the (<=1024) block sums; writes offsets[N]=total
__global__ void scan_blocksums(int* __restrict__ blockSums, int* __restrict__ blockOffs,
                               int nb, int* __restrict__ offsets, int N) {
    __shared__ int s[1024];
    int tid = threadIdx.x;
    s[tid] = (tid < nb) ? blockSums[tid] : 0;
    __syncthreads();
    for (int d = 1; d < 1024; d <<= 1) {
        int v = (tid >= d) ? s[tid - d] : 0;
        __syncthreads();
        s[tid] += v;
        __syncthreads();
    }
    if (tid < nb) blockOffs[tid] = (tid == 0) ? 0 : s[tid - 1];
    if (tid == 1023) offsets[N] = s[1023];
}

// K2c: in-block exclusive scan of 256 counts + block offset -> offsets; dinv = rsqrt(deg+1)
__global__ void scan_apply(const int* __restrict__ counts, const int* __restrict__ blockOffs,
                           int* __restrict__ offsets, float* __restrict__ dinv, int N) {
    __shared__ int s[256];
    int tid = threadIdx.x;
    int i = blockIdx.x * 256 + tid;
    int c = (i < N) ? counts[i] : 0;
    s[tid] = c;
    __syncthreads();
    for (int d = 1; d < 256; d <<= 1) {
        int v = (tid >= d) ? s[tid - d] : 0;
        __syncthreads();
        s[tid] += v;
        __syncthreads();
    }
    if (i < N) {
        offsets[i] = blockOffs[blockIdx.x] + s[tid] - c;  // exclusive
        dinv[i] = rsqrtf((float)(c + 1));                 // +1 self loop; deg >= 1
    }
}

// ---------------------------------------------------------------------------
// K3: scatter edge sources into CSR buckets
__global__ void scatter_kernel(const int* __restrict__ row, const int* __restrict__ col,
                               const int* __restrict__ offsets, int* __restrict__ cursor,
                               int* __restrict__ csr, int E) {
    int e = blockIdx.x * blockDim.x + threadIdx.x;
    if (e < E) {
        int c = col[e];
        int pos = offsets[c] + atomicAdd(&cursor[c], 1);
        csr[pos] = row[e];
    }
}

// ---------------------------------------------------------------------------
// K4: xs = (x @ W.T) * dinv[row]  — W-RESIDENT, 8 rows x 4 cols / thread.
// R6 post-mortem: __launch_bounds__(512,4) => 64-VGPR cap on this toolchain;
// the 8x4 tile needs ~106 VGPRs -> acc+pointers spilled to scratch = 650 MB
// of HBM spill traffic, 215us. (512,2) gives a 128-VGPR budget (R5-verified:
// compiler used 68 there, no spill). 8 rows (global broadcast) x 4 cols (LDS)
// halves LDS bytes/FLOP vs R5's 4x4: per k4 per wave 48 LDS-cyc vs 256 VALU
// -> CU demand 0.75 of LDS pipe, below saturation (R5 was 1.5x -> capped).
// XOR swizzle (k ^ ((j&31)<<2)) keeps float4 contiguity, 0 bank conflicts.
__global__ __launch_bounds__(512, 2) void gemm_kernel(
    const float* __restrict__ x, const float* __restrict__ W,
    const float* __restrict__ dinv, float* __restrict__ xs, int N) {
    __shared__ float sw[128 * 128];  // 64 KB, element (j,k) at j*128 + (k ^ ((j&31)<<2))
    int tid = threadIdx.x;
    int c  = tid & 31;   // column lane: cols c + 32q
    int rg = tid >> 5;   // row group in [0,16): rows rg + 16i, i in [0,8)

    // stage W once: 4096 float4s, 8 per thread
#pragma unroll
    for (int t = 0; t < 8; ++t) {
        int idx = tid + t * 512;                   // [0,4096)
        int j = idx >> 5, k4 = idx & 31;           // j in [0,128), k4 in [0,32)
        float4 v = ((const float4*)W)[idx];
        *((float4*)&sw[j * 128 + ((k4 * 4) ^ ((j & 31) << 2))]) = v;
    }
    __syncthreads();

    int cswz = c << 2;  // swizzle offset for this lane's columns (j&31 == c for all q)
    int r0 = blockIdx.x * 128;

    const float4* xr[8];
    bool valid[8];
#pragma unroll
    for (int i = 0; i < 8; ++i) {
        int grow = r0 + rg + 16 * i;
        valid[i] = (grow < N);
        xr[i] = (const float4*)&x[(size_t)(valid[i] ? grow : 0) * 128];
    }

    float acc[8][4];
#pragma unroll
    for (int i = 0; i < 8; ++i)
#pragma unroll
        for (int q = 0; q < 4; ++q) acc[i][q] = 0.f;

#pragma unroll 4
    for (int k4 = 0; k4 < 32; ++k4) {
        float4 wv[4], xv[8];
#pragma unroll
        for (int q = 0; q < 4; ++q)
            wv[q] = *((const float4*)&sw[(c + 32 * q) * 128 + ((k4 * 4) ^ cswz)]);
#pragma unroll
        for (int i = 0; i < 8; ++i) xv[i] = xr[i][k4];
#pragma unroll
        for (int i = 0; i < 8; ++i)
#pragma unroll
            for (int q = 0; q < 4; ++q)
                acc[i][q] += xv[i].x * wv[q].x + xv[i].y * wv[q].y +
                             xv[i].z * wv[q].z + xv[i].w * wv[q].w;
    }

#pragma unroll
    for (int i = 0; i < 8; ++i) {
        int grow = r0 + rg + 16 * i;
        if (valid[i]) {
            float dv = dinv[grow];
#pragma unroll
            for (int q = 0; q < 4; ++q)
                xs[(size_t)grow * 128 + c + 32 * q] = acc[i][q] * dv;
        }
    }
}

// ---------------------------------------------------------------------------
// K5: gather aggregation, one wave per node; pre[n] = dinv[n]*(xs[n] + sum xs[src])
__global__ void gather_kernel(const float* __restrict__ xs, const float* __restrict__ dinv,
                              const int* __restrict__ offsets, const int* __restrict__ csr,
                              float* __restrict__ pre, int N) {
    int lane = threadIdx.x & 63;
    int wid = (blockIdx.x * blockDim.x + threadIdx.x) >> 6;
    int nw  = (gridDim.x * blockDim.x) >> 6;
    const float2* xs2 = (const float2*)xs;
    float2* pre2 = (float2*)pre;
    for (int n = wid; n < N; n += nw) {
        int s = offsets[n], e = offsets[n + 1];
        float2 acc = xs2[n * 64 + lane];  // self loop term
        int p = s;
        for (; p + 8 <= e; p += 8) {      // 8-deep ILP on the random gathers
            int idx[8];
#pragma unroll
            for (int t = 0; t < 8; ++t) idx[t] = csr[p + t];
            float2 a[8];
#pragma unroll
            for (int t = 0; t < 8; ++t) a[t] = xs2[idx[t] * 64 + lane];
#pragma unroll
            for (int t = 0; t < 8; ++t) { acc.x += a[t].x; acc.y += a[t].y; }
        }
        for (; p < e; ++p) {
            float2 a = xs2[csr[p] * 64 + lane];
            acc.x += a.x; acc.y += a.y;
        }
        float dv = dinv[n];
        pre2[n * 64 + lane] = make_float2(acc.x * dv, acc.y * dv);
    }
}

// ---------------------------------------------------------------------------
// K6: column sums + total sum of squares (for PairNorm via moment identity)
__global__ void moments_kernel(const float* __restrict__ pre, float* __restrict__ colsum,
                               float* __restrict__ sumsq, int total) {
    __shared__ float red[256];
    int tid = blockIdx.x * blockDim.x + threadIdx.x;
    int stride = gridDim.x * blockDim.x;  // multiple of 128 -> column fixed per thread
    float cs = 0.f, ss = 0.f;
    for (int i = tid; i < total; i += stride) {
        float v = pre[i];
        cs += v; ss += v * v;
    }
    red[threadIdx.x] = cs;
    __syncthreads();
    if (threadIdx.x < 128)
        atomicAdd(&colsum[threadIdx.x], red[threadIdx.x] + red[threadIdx.x + 128]);
    __syncthreads();
    red[threadIdx.x] = ss;
    __syncthreads();
    for (int d = 128; d > 0; d >>= 1) {
        if (threadIdx.x < d) red[threadIdx.x] += red[threadIdx.x + d];
        __syncthreads();
    }
    if (threadIdx.x == 0) atomicAdd(sumsq, red[0]);
}

// ---------------------------------------------------------------------------
// K7: tiny param kernel: colmean and global scale s
__global__ void params_kernel(const float* __restrict__ colsum, const float* __restrict__ sumsq,
                              float* __restrict__ mparams, int N) {
    int j = threadIdx.x;  // 128 threads
    float m = colsum[j] / (float)N;
    mparams[j] = m;
    __shared__ float red[128];
    red[j] = m * m;
    __syncthreads();
    for (int d = 64; d > 0; d >>= 1) {
        if (j < d) red[j] += red[j + d];
        __syncthreads();
    }
    if (j == 0) {
        float tot = sumsq[0] - (float)N * red[0];  // sum (out - m)^2
        mparams[128] = rsqrtf(EPS + tot / (float)N);
    }
}

// ---------------------------------------------------------------------------
// K8: in-place PairNorm apply + relu + residual:  y=(v-m_j)*s; out = y>0 ? 2y : y
__global__ void final_kernel(float* __restrict__ out, const float* __restrict__ mparams,
                             int total) {
    __shared__ float sm[129];
    if (threadIdx.x < 129) sm[threadIdx.x] = mparams[threadIdx.x];
    __syncthreads();
    float s = sm[128];
    int tid = blockIdx.x * blockDim.x + threadIdx.x;
    int stride = gridDim.x * blockDim.x;
    for (int i = tid; i < total; i += stride) {
        float y = (out[i] - sm[i & 127]) * s;
        out[i] = y > 0.f ? 2.f * y : y;
    }
}

// ---------------------------------------------------------------------------
extern "C" void kernel_launch(void* const* d_in, const int* in_sizes, int n_in,
                              void* d_out, int out_size, void* d_ws, size_t ws_size,
                              hipStream_t stream) {
    const float* x = (const float*)d_in[0];
    const float* W = (const float*)d_in[1];
    const int* ei  = (const int*)d_in[2];
    int N = in_sizes[0] / 128;
    int E = in_sizes[2] / 2;
    const int* row = ei;        // edge_index[0] = source
    const int* col = ei + E;    // edge_index[1] = aggregation target
    float* out = (float*)d_out;

    int nb = (N + 255) / 256;   // scan blocks (196 for N=50000; must be <= 1024)

    // workspace layout (all 4-byte elements)
    float* xs        = (float*)d_ws;            // N*128
    float* dinv      = xs + (size_t)N * 128;    // N
    int*   counts    = (int*)(dinv + N);        // N    [zeroed]
    int*   cursor    = counts + N;              // N    [zeroed]
    float* colsum    = (float*)(cursor + N);    // 128  [zeroed]
    float* sumsq     = colsum + 128;            // 1    [zeroed]
    int*   offsets   = (int*)(sumsq + 1);       // N+1
    int*   csr       = offsets + (N + 1);       // E
    float* mparams   = (float*)(csr + E);       // 129
    int*   blockSums = (int*)(mparams + 129);   // nb
    int*   blockOffs = blockSums + nb;          // nb

    hipMemsetAsync(counts, 0, (size_t)(2 * N + 129) * 4, stream);

    count_kernel  <<<(E + 255) / 256, 256, 0, stream>>>(col, counts, E);
    scan_reduce   <<<nb, 256, 0, stream>>>(counts, blockSums, N);
    scan_blocksums<<<1, 1024, 0, stream>>>(blockSums, blockOffs, nb, offsets, N);
    scan_apply    <<<nb, 256, 0, stream>>>(counts, blockOffs, offsets, dinv, N);
    scatter_kernel<<<(E + 255) / 256, 256, 0, stream>>>(row, col, offsets, cursor, csr, E);
    gemm_kernel   <<<(N + 127) / 128, 512, 0, stream>>>(x, W, dinv, xs, N);
    gather_kernel <<<2048, 256, 0, stream>>>(xs, dinv, offsets, csr, out, N);
    moments_kernel<<<512, 256, 0, stream>>>(out, colsum, sumsq, N * 128);
    params_kernel <<<1, 128, 0, stream>>>(colsum, sumsq, mparams, N);
    final_kernel  <<<1024, 256, 0, stream>>>(out, mparams, N * 128);
}